// Round 3
// baseline (299.130 us; speedup 1.0000x reference)
//
#include <hip/hip_runtime.h>

#define BATCH 32
#define SEQT  2048
#define INSZ  256
#define RSV   512
#define MTOT  (BATCH * SEQT)   // 65536 GEMM rows
#define BM 128
#define BN 128
#define BK 32
#define LSA 40     // fast-path A LDS row: 32 f16 + 8 pad (80 B)
#define PADM 65600 // u16T row stride in elems: 65536 + 64 (131200 B, breaks 128KB channel alias)

#define K2LOG2E 2.8853900817779268f  // 2*log2(e)

using f16x8 = __attribute__((ext_vector_type(8))) _Float16;
using f16x4 = __attribute__((ext_vector_type(4))) _Float16;
using f32x4 = __attribute__((ext_vector_type(4))) float;

typedef __attribute__((address_space(1))) unsigned int as1_u32;
typedef __attribute__((address_space(3))) unsigned int as3_u32;
#define GLDS16(gp, lp) __builtin_amdgcn_global_load_lds((as1_u32*)(gp), (as3_u32*)(lp), 16, 0, 0)

// tanh step: s' = tanh(d*s + u) via exp2; dK = d*2log2e, u pre-scaled by 2log2e inside.
static __device__ __forceinline__ float esn_step(float s, float u, float dK) {
    float z  = __builtin_fmaf(dK, s, u * K2LOG2E);
    float e  = __builtin_amdgcn_exp2f(z);
    float rc = __builtin_amdgcn_rcpf(1.0f + e);
    return __builtin_fmaf(-2.0f, rc, 1.0f);
}

// ---------------- fast path ----------------

// W [512][256] fp32 -> W16 [2][512][256] f16 (hi plane, lo plane)
__global__ __launch_bounds__(256) void esn_convw(const float* __restrict__ W,
                                                 _Float16* __restrict__ W16) {
    const int i = blockIdx.x * 256 + threadIdx.x;     // 0..32767, 4 elems each
    float4 v = *(const float4*)(W + (size_t)i * 4);
    float w4[4] = {v.x, v.y, v.z, v.w};
    f16x4 h, l;
    #pragma unroll
    for (int j = 0; j < 4; ++j) {
        _Float16 hh = (_Float16)w4[j];
        h[j] = hh;
        l[j] = (_Float16)(w4[j] - (float)hh);
    }
    *(f16x4*)(W16 + (size_t)i * 4) = h;
    *(f16x4*)(W16 + (size_t)RSV * INSZ + (size_t)i * 4) = l;
}

// u[m][n] = sum_k X[m][k]*W[n][k]; 2-pass f16 (W hi/lo pre-split), B via global_load_lds,
// A reg-converted fp32->f16. Output: u16T[n][m] f16 (transposed, padded rows).
__global__ __launch_bounds__(256) void esn_gemm_f(const float* __restrict__ X,
                                                  const _Float16* __restrict__ W16,
                                                  _Float16* __restrict__ U16T) {
    __shared__ _Float16 Ash[BM * LSA];
    __shared__ _Float16 Bh[BM * BK];   // linear (global_load_lds dest)
    __shared__ _Float16 Bl[BM * BK];

    const int tid  = threadIdx.x;
    const int lane = tid & 63;
    const int wid  = tid >> 6;
    const int wr   = wid >> 1, wc = wid & 1;
    // chunked XCD swizzle: XCD x gets bm in [x*64, x*64+64), bn-siblings adjacent
    const int lgc = (blockIdx.x & 7) * 256 + (blockIdx.x >> 3);
    const int bm = lgc >> 2, bn = lgc & 3;

    const int srow = tid >> 3;        // 0..31
    const int scol = (tid & 7) * 4;   // 0,4,...,28

    f32x4 acc[4][4] = {};

    for (int ks = 0; ks < INSZ / BK; ++ks) {
        __syncthreads();
        // ---- B stage: direct global->LDS DMA (no VALU) ----
        #pragma unroll
        for (int q = 0; q < 2; ++q) {
            const int c   = (wid * 2 + q) * 64 + lane;   // 0..511 chunk id
            const int row = c >> 2, col = (c & 3) * 8;
            const _Float16* gh = W16 + (size_t)(bn * BM + row) * INSZ + ks * BK + col;
            GLDS16(gh, &Bh[(wid * 2 + q) * 512]);
            GLDS16(gh + (size_t)RSV * INSZ, &Bl[(wid * 2 + q) * 512]);
        }
        // ---- A stage: fp32 -> f16 in regs -> LDS ----
        #pragma unroll
        for (int p = 0; p < 4; ++p) {
            const int row = srow + p * 32;
            float4 av = *(const float4*)(X + (size_t)(bm * BM + row) * INSZ + ks * BK + scol);
            float a4[4] = {av.x, av.y, av.z, av.w};
            f16x4 ah;
            #pragma unroll
            for (int j = 0; j < 4; ++j) ah[j] = (_Float16)a4[j];
            *(f16x4*)&Ash[row * LSA + scol] = ah;
        }
        __syncthreads();

        // ---- fragments + 2-pass MFMA ----
        f16x8 af[4], bfh[4], bfl[4];
        #pragma unroll
        for (int m = 0; m < 4; ++m)
            af[m] = *(const f16x8*)&Ash[(wr * 64 + m * 16 + (lane & 15)) * LSA + (lane >> 4) * 8];
        #pragma unroll
        for (int n = 0; n < 4; ++n) {
            const int rr = (wc * 64 + n * 16 + (lane & 15)) * BK + (lane >> 4) * 8;
            bfh[n] = *(const f16x8*)&Bh[rr];
            bfl[n] = *(const f16x8*)&Bl[rr];
        }
        #pragma unroll
        for (int m = 0; m < 4; ++m)
            #pragma unroll
            for (int n = 0; n < 4; ++n) {
                acc[m][n] = __builtin_amdgcn_mfma_f32_16x16x32_f16(af[m], bfh[n], acc[m][n], 0, 0, 0);
                acc[m][n] = __builtin_amdgcn_mfma_f32_16x16x32_f16(af[m], bfl[n], acc[m][n], 0, 0, 0);
            }
    }

    // ---- epilogue: C/D layout col=lane&15, row=(lane>>4)*4+j; store f16 transposed ----
    #pragma unroll
    for (int m = 0; m < 4; ++m) {
        const int row0 = bm * BM + wr * 64 + m * 16 + (lane >> 4) * 4;
        #pragma unroll
        for (int n = 0; n < 4; ++n) {
            const int col = bn * BN + wc * 64 + n * 16 + (lane & 15);
            f32x4 v = acc[m][n];
            f16x4 o;
            #pragma unroll
            for (int j = 0; j < 4; ++j) o[j] = (_Float16)v[j];
            *(f16x4*)(U16T + (size_t)col * PADM + row0) = o;
        }
    }
}

// Parallel-in-time recurrence: 8 segments of 256 steps, 32-step warmup from zero state
// (|d|<=0.5 => warmup error <= 2^-32). Reads u16T[r][t] (contiguous per thread),
// writes OUT[b][t][r] fp32 coalesced.
__global__ __launch_bounds__(256) void esn_recur_f(const _Float16* __restrict__ U16T,
                                                   const float* __restrict__ D,
                                                   float* __restrict__ OUT) {
    const int tid  = threadIdx.x;
    const int half = blockIdx.x & 1;
    const int pair = blockIdx.x >> 1;      // b*8 + seg
    const int b    = pair >> 3, seg = pair & 7;
    const int r    = half * 256 + tid;

    const _Float16* urow = U16T + (size_t)r * PADM + b * SEQT;  // urow[t] = u[b,t,r]
    float* obase = OUT + (size_t)b * SEQT * RSV + r;            // obase[t*RSV]
    const float dK = D[r] * K2LOG2E;
    const int t0 = seg * 256;

    float s = 0.0f;
    if (seg) {   // warmup t = t0-32 .. t0-1 (reads u[t0-31..t0])
        #pragma unroll
        for (int k = 0; k < 32; ++k)
            s = esn_step(s, (float)urow[t0 - 31 + k], dK);
    }

    _Float16 bufA[8], bufB[8];
    #pragma unroll
    for (int j = 0; j < 8; ++j) bufA[j] = urow[t0 + 1 + j];
    #pragma unroll
    for (int j = 0; j < 8; ++j) bufB[j] = urow[t0 + 9 + j];

#define PROC8F(buf, tt) do {                                  \
    _Pragma("unroll")                                         \
    for (int j = 0; j < 8; ++j) {                             \
        s = esn_step(s, (float)buf[j], dK);                   \
        obase[(size_t)((tt) + j) * RSV] = s;                  \
        int idx = (tt) + j + 17;                              \
        idx = idx < SEQT ? idx : SEQT - 1;                    \
        buf[j] = urow[idx];                                   \
    }                                                         \
} while (0)

    int t = t0;
    for (int it = 0; it < 16; ++it) {   // 16*16 = 256 steps
        PROC8F(bufA, t);
        PROC8F(bufB, t + 8);
        t += 16;
    }
#undef PROC8F
    // last timestep is all zeros (overwrites seg-7's garbage step at t=2047)
    if (seg == 7) obase[(size_t)(SEQT - 1) * RSV] = 0.0f;
}

// ---------------- fallback path (round-2 kernels, in-place on d_out) ----------------

__global__ __launch_bounds__(256) void esn_gemm_fb(const float* __restrict__ X,
                                                   const float* __restrict__ W,
                                                   float* __restrict__ U) {
    __shared__ _Float16 Ash[BM * LSA];
    __shared__ _Float16 Bsh[BN * 72];

    const int tid  = threadIdx.x;
    const int lane = tid & 63;
    const int wid  = tid >> 6;
    const int wr   = wid >> 1, wc = wid & 1;
    const int bm   = blockIdx.x >> 2, bn = blockIdx.x & 3;
    const int srow = tid >> 3;
    const int scol = (tid & 7) * 4;

    f32x4 acc[4][4] = {};

    for (int ks = 0; ks < INSZ / BK; ++ks) {
        __syncthreads();
        #pragma unroll
        for (int p = 0; p < 4; ++p) {
            const int row = srow + p * 32;
            float4 av = *(const float4*)(X + (size_t)(bm * BM + row) * INSZ + ks * BK + scol);
            float4 bv = *(const float4*)(W + (size_t)(bn * BN + row) * INSZ + ks * BK + scol);
            float a4[4] = {av.x, av.y, av.z, av.w};
            float b4[4] = {bv.x, bv.y, bv.z, bv.w};
            f16x4 ah, bh, bl;
            #pragma unroll
            for (int j = 0; j < 4; ++j) {
                ah[j] = (_Float16)a4[j];
                _Float16 h = (_Float16)b4[j];
                bh[j] = h;
                bl[j] = (_Float16)(b4[j] - (float)h);
            }
            *(f16x4*)&Ash[row * LSA + scol] = ah;
            *(f16x4*)&Bsh[row * 72 + scol] = bh;
            *(f16x4*)&Bsh[row * 72 + 32 + scol] = bl;
        }
        __syncthreads();

        f16x8 af[4], bfh[4], bfl[4];
        #pragma unroll
        for (int m = 0; m < 4; ++m)
            af[m] = *(const f16x8*)&Ash[(wr * 64 + m * 16 + (lane & 15)) * LSA + (lane >> 4) * 8];
        #pragma unroll
        for (int n = 0; n < 4; ++n) {
            const _Float16* p = &Bsh[(wc * 64 + n * 16 + (lane & 15)) * 72 + (lane >> 4) * 8];
            bfh[n] = *(const f16x8*)p;
            bfl[n] = *(const f16x8*)(p + 32);
        }
        #pragma unroll
        for (int m = 0; m < 4; ++m)
            #pragma unroll
            for (int n = 0; n < 4; ++n) {
                acc[m][n] = __builtin_amdgcn_mfma_f32_16x16x32_f16(af[m], bfh[n], acc[m][n], 0, 0, 0);
                acc[m][n] = __builtin_amdgcn_mfma_f32_16x16x32_f16(af[m], bfl[n], acc[m][n], 0, 0, 0);
            }
    }

    #pragma unroll
    for (int m = 0; m < 4; ++m) {
        const int row = bm * BM + wr * 64 + m * 16 + (lane >> 4) * 4;
        #pragma unroll
        for (int n = 0; n < 4; ++n) {
            const int col = bn * BN + wc * 64 + n * 16 + (lane & 15);
            f32x4 v = acc[m][n];
            #pragma unroll
            for (int j = 0; j < 4; ++j)
                U[(size_t)(row + j) * RSV + col] = v[j];
        }
    }
}

__global__ __launch_bounds__(64) void esn_recur_fb(float* __restrict__ OUT,
                                                   const float* __restrict__ D) {
    const int gid = blockIdx.x * 64 + threadIdx.x;
    const int b = gid >> 9;
    const int r = gid & (RSV - 1);
    float* base = OUT + (size_t)b * SEQT * RSV + r;
    const float dK = D[r] * K2LOG2E;
    float s = 0.0f;

    float bA[8], bB[8], bC[8], bD[8];
    #pragma unroll
    for (int j = 0; j < 8; ++j) bA[j] = base[(size_t)(1 + j) * RSV];
    #pragma unroll
    for (int j = 0; j < 8; ++j) bB[j] = base[(size_t)(9 + j) * RSV];
    #pragma unroll
    for (int j = 0; j < 8; ++j) bC[j] = base[(size_t)(17 + j) * RSV];
    #pragma unroll
    for (int j = 0; j < 8; ++j) bD[j] = base[(size_t)(25 + j) * RSV];

#define PROC8B(buf, tt) do {                                  \
    _Pragma("unroll")                                         \
    for (int j = 0; j < 8; ++j) {                             \
        s = esn_step(s, buf[j], dK);                          \
        base[(size_t)((tt) + j) * RSV] = s;                   \
        int idx = (tt) + 33 + j;                              \
        idx = idx < SEQT ? idx : SEQT - 1;                    \
        buf[j] = base[(size_t)idx * RSV];                     \
    }                                                         \
} while (0)

    int t = 0;
    for (int it = 0; it < 63; ++it) {
        PROC8B(bA, t);
        PROC8B(bB, t + 8);
        PROC8B(bC, t + 16);
        PROC8B(bD, t + 24);
        t += 32;
    }
#undef PROC8B
    #pragma unroll
    for (int j = 0; j < 8; ++j) { s = esn_step(s, bA[j], dK); base[(size_t)(2016 + j) * RSV] = s; }
    #pragma unroll
    for (int j = 0; j < 8; ++j) { s = esn_step(s, bB[j], dK); base[(size_t)(2024 + j) * RSV] = s; }
    #pragma unroll
    for (int j = 0; j < 8; ++j) { s = esn_step(s, bC[j], dK); base[(size_t)(2032 + j) * RSV] = s; }
    #pragma unroll
    for (int j = 0; j < 7; ++j) { s = esn_step(s, bD[j], dK); base[(size_t)(2040 + j) * RSV] = s; }

    base[(size_t)(SEQT - 1) * RSV] = 0.0f;
}

extern "C" void kernel_launch(void* const* d_in, const int* in_sizes, int n_in,
                              void* d_out, int out_size, void* d_ws, size_t ws_size,
                              hipStream_t stream) {
    const float* X = (const float*)d_in[0];   // [32,2048,256] fp32
    const float* W = (const float*)d_in[1];   // [512,256] fp32
    const float* D = (const float*)d_in[2];   // [512] fp32
    float* OUT = (float*)d_out;               // [32,2048,512] fp32

    const size_t W16_BYTES  = (size_t)2 * RSV * INSZ * sizeof(_Float16);   // 512 KB
    const size_t U16T_BYTES = (size_t)RSV * PADM * sizeof(_Float16);       // ~64 MB
    if (ws_size >= W16_BYTES + U16T_BYTES) {
        _Float16* W16  = (_Float16*)d_ws;
        _Float16* U16T = (_Float16*)((char*)d_ws + W16_BYTES);
        esn_convw<<<dim3(RSV * INSZ / 4 / 256), dim3(256), 0, stream>>>(W, W16);
        esn_gemm_f<<<dim3((MTOT / BM) * (RSV / BN)), dim3(256), 0, stream>>>(X, W16, U16T);
        esn_recur_f<<<dim3(BATCH * 8 * 2), dim3(256), 0, stream>>>(U16T, D, OUT);
    } else {
        esn_gemm_fb<<<dim3((MTOT / BM) * (RSV / BN)), dim3(256), 0, stream>>>(X, W, OUT);
        esn_recur_fb<<<dim3(BATCH * RSV / 64), dim3(64), 0, stream>>>(OUT, D);
    }
}

// Round 4
// 245.629 us; speedup vs baseline: 1.2178x; 1.2178x over previous
//
#include <hip/hip_runtime.h>

#define BATCH 32
#define SEQT  2048
#define INSZ  256
#define RSV   512
#define MTOT  (BATCH * SEQT)   // 65536 GEMM rows
#define BM 128
#define BN 128
#define BK 32
#define LSA 40       // fallback A LDS row stride (f16)
#define ASTR 1040    // fast-path A LDS q-stride in f16 (2080 B: q-groups offset 8 banks)
#define LOPLANE 131072  // f16 offset of lo plane in W16T (4*8*512*8)

#define K2LOG2E 2.8853900817779268f  // 2*log2(e)

using f16x8 = __attribute__((ext_vector_type(8))) _Float16;
using f16x4 = __attribute__((ext_vector_type(4))) _Float16;
using f32x4 = __attribute__((ext_vector_type(4))) float;

typedef __attribute__((address_space(1))) unsigned int as1_u32;
typedef __attribute__((address_space(3))) unsigned int as3_u32;
#define GLDS16(gp, lp) __builtin_amdgcn_global_load_lds((as1_u32*)(gp), (as3_u32*)(lp), 16, 0, 0)

// tanh step: s' = tanh(d*s + u); dK = d*2log2e.
static __device__ __forceinline__ float esn_step(float s, float u, float dK) {
    float z  = __builtin_fmaf(dK, s, u * K2LOG2E);
    float e  = __builtin_amdgcn_exp2f(z);
    float rc = __builtin_amdgcn_rcpf(1.0f + e);
    return __builtin_fmaf(-2.0f, rc, 1.0f);
}

// ---------------- fast path ----------------

// W [512][256] fp32 -> W16T: GLDS-chunk-major hi/lo f16 planes.
// Chunk i (16 B): bn=i>>12, ks=(i>>9)&7, c=i&511, q=c>>7, row=c&127;
// holds W[bn*128+row][ks*32+q*8 .. +7]. Linear GLDS write then lands [q][row] in LDS.
__global__ __launch_bounds__(256) void esn_convw(const float* __restrict__ W,
                                                 _Float16* __restrict__ W16T) {
    const int i = blockIdx.x * 256 + threadIdx.x;   // 0..16383
    const int bn = i >> 12, ks = (i >> 9) & 7, c = i & 511;
    const int q = c >> 7, row = c & 127;
    const float* src = W + (size_t)(bn * 128 + row) * INSZ + ks * 32 + q * 8;
    float4 v0 = *(const float4*)src;
    float4 v1 = *(const float4*)(src + 4);
    float w8[8] = {v0.x, v0.y, v0.z, v0.w, v1.x, v1.y, v1.z, v1.w};
    f16x8 h, l;
    #pragma unroll
    for (int j = 0; j < 8; ++j) {
        _Float16 hh = (_Float16)w8[j];
        h[j] = hh;
        l[j] = (_Float16)(w8[j] - (float)hh);
    }
    *(f16x8*)(W16T + (size_t)i * 8) = h;
    *(f16x8*)(W16T + LOPLANE + (size_t)i * 8) = l;
}

// u[m][n] = sum_k X[m][k]*W[n][k]; 2-pass f16 (W hi/lo pre-tiled), B via global_load_lds
// (coalesced source, q-major LDS => 2-way-free ds_read_b128), A reg-converted into padded
// q-major LDS. Output u16 [m][n] f16.
__global__ __launch_bounds__(256) void esn_gemm_f(const float* __restrict__ X,
                                                  const _Float16* __restrict__ W16T,
                                                  _Float16* __restrict__ U16) {
    __shared__ _Float16 Ash[4 * ASTR];   // 8320 B, [q][row][8], q-stride 2080 B
    __shared__ _Float16 Bh[4096];        // 8192 B, [q][row][8] linear (GLDS dest)
    __shared__ _Float16 Bl[4096];

    const int tid  = threadIdx.x;
    const int lane = tid & 63;
    const int wid  = tid >> 6;
    const int wr   = wid >> 1, wc = wid & 1;
    // chunked XCD swizzle: bn-siblings of one bm adjacent on one XCD
    const int lgc = (blockIdx.x & 7) * 256 + (blockIdx.x >> 3);
    const int bm = lgc >> 2, bn = lgc & 3;

    const int srow = tid >> 3;            // 0..31
    const int scol = (tid & 7) * 4;       // 0,4,...,28
    const int qa   = scol >> 3;           // 0..3
    const int ha   = (scol >> 2) & 1;     // half within 8-f16 chunk

    f32x4 acc[4][4] = {};

    for (int ks = 0; ks < INSZ / BK; ++ks) {
        __syncthreads();
        // ---- B stage: direct global->LDS DMA, coalesced 16B/lane ----
        #pragma unroll
        for (int j = 0; j < 2; ++j) {
            const int cbase = (wid * 2 + j) * 64;
            const _Float16* gh = W16T + ((size_t)(bn * 8 + ks) * 512 + cbase + lane) * 8;
            GLDS16(gh, &Bh[cbase * 8]);
            GLDS16(gh + LOPLANE, &Bl[cbase * 8]);
        }
        // ---- A stage: coalesced fp32 read -> f16 -> q-major LDS ----
        #pragma unroll
        for (int p = 0; p < 4; ++p) {
            const int row = srow + p * 32;
            float4 av = *(const float4*)(X + (size_t)(bm * BM + row) * INSZ + ks * BK + scol);
            float a4[4] = {av.x, av.y, av.z, av.w};
            f16x4 ah;
            #pragma unroll
            for (int j = 0; j < 4; ++j) ah[j] = (_Float16)a4[j];
            *(f16x4*)&Ash[qa * ASTR + row * 8 + ha * 4] = ah;
        }
        __syncthreads();

        // ---- fragments (2-way bank-free) + 2-pass MFMA ----
        f16x8 af[4], bfh[4], bfl[4];
        const int qf = lane >> 4;
        #pragma unroll
        for (int m = 0; m < 4; ++m)
            af[m] = *(const f16x8*)&Ash[qf * ASTR + (wr * 64 + m * 16 + (lane & 15)) * 8];
        #pragma unroll
        for (int n = 0; n < 4; ++n) {
            const int rr = qf * 1024 + (wc * 64 + n * 16 + (lane & 15)) * 8;
            bfh[n] = *(const f16x8*)&Bh[rr];
            bfl[n] = *(const f16x8*)&Bl[rr];
        }
        #pragma unroll
        for (int m = 0; m < 4; ++m)
            #pragma unroll
            for (int n = 0; n < 4; ++n) {
                acc[m][n] = __builtin_amdgcn_mfma_f32_16x16x32_f16(af[m], bfh[n], acc[m][n], 0, 0, 0);
                acc[m][n] = __builtin_amdgcn_mfma_f32_16x16x32_f16(af[m], bfl[n], acc[m][n], 0, 0, 0);
            }
    }

    // ---- epilogue: C/D col=lane&15, row=(lane>>4)*4+j; u16 [m][r] f16 stores ----
    #pragma unroll
    for (int m = 0; m < 4; ++m) {
        const int row0 = bm * BM + wr * 64 + m * 16 + (lane >> 4) * 4;
        #pragma unroll
        for (int n = 0; n < 4; ++n) {
            const int col = bn * BN + wc * 64 + n * 16 + (lane & 15);
            f32x4 v = acc[m][n];
            #pragma unroll
            for (int j = 0; j < 4; ++j)
                U16[(size_t)(row0 + j) * RSV + col] = (_Float16)v[j];
        }
    }
}

// Parallel-in-time recurrence: 8 segments of 256 steps, 32-step warmup from zero
// (|d|<=0.5 => warmup error <= 2^-32). u16 [b][t][r]: wave reads 64 consecutive r
// per step (coalesced 128B); OUT writes coalesced 256B. 512 blocks -> 8 waves/CU TLP,
// 16-deep register prefetch ILP.
__global__ __launch_bounds__(256) void esn_recur_f(const _Float16* __restrict__ U16,
                                                   const float* __restrict__ D,
                                                   float* __restrict__ OUT) {
    const int tid  = threadIdx.x;
    const int b    = blockIdx.x >> 4;
    const int seg  = (blockIdx.x >> 1) & 7;
    const int half = blockIdx.x & 1;
    const int r    = half * 256 + tid;

    const _Float16* ub = U16 + (size_t)b * SEQT * RSV + r;   // ub[t*RSV]
    float* ob = OUT + (size_t)b * SEQT * RSV + r;
    const float dK = D[r] * K2LOG2E;
    const int t0 = seg * 256;

    float s = 0.0f;
    if (seg) {   // warmup t = t0-32 .. t0-1 (uses u[t0-31..t0])
        #pragma unroll 8
        for (int k = 0; k < 32; ++k)
            s = esn_step(s, (float)ub[(size_t)(t0 - 31 + k) * RSV], dK);
    }

    _Float16 bufA[8], bufB[8];
    #pragma unroll
    for (int j = 0; j < 8; ++j) bufA[j] = ub[(size_t)(t0 + 1 + j) * RSV];
    #pragma unroll
    for (int j = 0; j < 8; ++j) bufB[j] = ub[(size_t)(t0 + 9 + j) * RSV];

#define PROC8F(buf, tt) do {                                  \
    _Pragma("unroll")                                         \
    for (int j = 0; j < 8; ++j) {                             \
        s = esn_step(s, (float)buf[j], dK);                   \
        ob[(size_t)((tt) + j) * RSV] = s;                     \
        int idx = (tt) + j + 17;                              \
        idx = idx < SEQT ? idx : SEQT - 1;                    \
        buf[j] = ub[(size_t)idx * RSV];                       \
    }                                                         \
} while (0)

    int t = t0;
    for (int it = 0; it < 16; ++it) {   // 16*16 = 256 steps
        PROC8F(bufA, t);
        PROC8F(bufB, t + 8);
        t += 16;
    }
#undef PROC8F
    // final timestep is all zeros (overwrites seg-7's garbage step at t=2047)
    if (seg == 7) ob[(size_t)(SEQT - 1) * RSV] = 0.0f;
}

// ---------------- fallback path (round-2 kernels, in-place on d_out) ----------------

__global__ __launch_bounds__(256) void esn_gemm_fb(const float* __restrict__ X,
                                                   const float* __restrict__ W,
                                                   float* __restrict__ U) {
    __shared__ _Float16 Ash[BM * LSA];
    __shared__ _Float16 Bsh[BN * 72];

    const int tid  = threadIdx.x;
    const int lane = tid & 63;
    const int wid  = tid >> 6;
    const int wr   = wid >> 1, wc = wid & 1;
    const int bm   = blockIdx.x >> 2, bn = blockIdx.x & 3;
    const int srow = tid >> 3;
    const int scol = (tid & 7) * 4;

    f32x4 acc[4][4] = {};

    for (int ks = 0; ks < INSZ / BK; ++ks) {
        __syncthreads();
        #pragma unroll
        for (int p = 0; p < 4; ++p) {
            const int row = srow + p * 32;
            float4 av = *(const float4*)(X + (size_t)(bm * BM + row) * INSZ + ks * BK + scol);
            float4 bv = *(const float4*)(W + (size_t)(bn * BN + row) * INSZ + ks * BK + scol);
            float a4[4] = {av.x, av.y, av.z, av.w};
            float b4[4] = {bv.x, bv.y, bv.z, bv.w};
            f16x4 ah, bh, bl;
            #pragma unroll
            for (int j = 0; j < 4; ++j) {
                ah[j] = (_Float16)a4[j];
                _Float16 h = (_Float16)b4[j];
                bh[j] = h;
                bl[j] = (_Float16)(b4[j] - (float)h);
            }
            *(f16x4*)&Ash[row * LSA + scol] = ah;
            *(f16x4*)&Bsh[row * 72 + scol] = bh;
            *(f16x4*)&Bsh[row * 72 + 32 + scol] = bl;
        }
        __syncthreads();

        f16x8 af[4], bfh[4], bfl[4];
        #pragma unroll
        for (int m = 0; m < 4; ++m)
            af[m] = *(const f16x8*)&Ash[(wr * 64 + m * 16 + (lane & 15)) * LSA + (lane >> 4) * 8];
        #pragma unroll
        for (int n = 0; n < 4; ++n) {
            const _Float16* p = &Bsh[(wc * 64 + n * 16 + (lane & 15)) * 72 + (lane >> 4) * 8];
            bfh[n] = *(const f16x8*)p;
            bfl[n] = *(const f16x8*)(p + 32);
        }
        #pragma unroll
        for (int m = 0; m < 4; ++m)
            #pragma unroll
            for (int n = 0; n < 4; ++n) {
                acc[m][n] = __builtin_amdgcn_mfma_f32_16x16x32_f16(af[m], bfh[n], acc[m][n], 0, 0, 0);
                acc[m][n] = __builtin_amdgcn_mfma_f32_16x16x32_f16(af[m], bfl[n], acc[m][n], 0, 0, 0);
            }
    }

    #pragma unroll
    for (int m = 0; m < 4; ++m) {
        const int row = bm * BM + wr * 64 + m * 16 + (lane >> 4) * 4;
        #pragma unroll
        for (int n = 0; n < 4; ++n) {
            const int col = bn * BN + wc * 64 + n * 16 + (lane & 15);
            f32x4 v = acc[m][n];
            #pragma unroll
            for (int j = 0; j < 4; ++j)
                U[(size_t)(row + j) * RSV + col] = v[j];
        }
    }
}

__global__ __launch_bounds__(64) void esn_recur_fb(float* __restrict__ OUT,
                                                   const float* __restrict__ D) {
    const int gid = blockIdx.x * 64 + threadIdx.x;
    const int b = gid >> 9;
    const int r = gid & (RSV - 1);
    float* base = OUT + (size_t)b * SEQT * RSV + r;
    const float dK = D[r] * K2LOG2E;
    float s = 0.0f;

    float bA[8], bB[8], bC[8], bD[8];
    #pragma unroll
    for (int j = 0; j < 8; ++j) bA[j] = base[(size_t)(1 + j) * RSV];
    #pragma unroll
    for (int j = 0; j < 8; ++j) bB[j] = base[(size_t)(9 + j) * RSV];
    #pragma unroll
    for (int j = 0; j < 8; ++j) bC[j] = base[(size_t)(17 + j) * RSV];
    #pragma unroll
    for (int j = 0; j < 8; ++j) bD[j] = base[(size_t)(25 + j) * RSV];

#define PROC8B(buf, tt) do {                                  \
    _Pragma("unroll")                                         \
    for (int j = 0; j < 8; ++j) {                             \
        s = esn_step(s, buf[j], dK);                          \
        base[(size_t)((tt) + j) * RSV] = s;                   \
        int idx = (tt) + 33 + j;                              \
        idx = idx < SEQT ? idx : SEQT - 1;                    \
        buf[j] = base[(size_t)idx * RSV];                     \
    }                                                         \
} while (0)

    int t = 0;
    for (int it = 0; it < 63; ++it) {
        PROC8B(bA, t);
        PROC8B(bB, t + 8);
        PROC8B(bC, t + 16);
        PROC8B(bD, t + 24);
        t += 32;
    }
#undef PROC8B
    #pragma unroll
    for (int j = 0; j < 8; ++j) { s = esn_step(s, bA[j], dK); base[(size_t)(2016 + j) * RSV] = s; }
    #pragma unroll
    for (int j = 0; j < 8; ++j) { s = esn_step(s, bB[j], dK); base[(size_t)(2024 + j) * RSV] = s; }
    #pragma unroll
    for (int j = 0; j < 8; ++j) { s = esn_step(s, bC[j], dK); base[(size_t)(2032 + j) * RSV] = s; }
    #pragma unroll
    for (int j = 0; j < 7; ++j) { s = esn_step(s, bD[j], dK); base[(size_t)(2040 + j) * RSV] = s; }

    base[(size_t)(SEQT - 1) * RSV] = 0.0f;
}

extern "C" void kernel_launch(void* const* d_in, const int* in_sizes, int n_in,
                              void* d_out, int out_size, void* d_ws, size_t ws_size,
                              hipStream_t stream) {
    const float* X = (const float*)d_in[0];   // [32,2048,256] fp32
    const float* W = (const float*)d_in[1];   // [512,256] fp32
    const float* D = (const float*)d_in[2];   // [512] fp32
    float* OUT = (float*)d_out;               // [32,2048,512] fp32

    const size_t W16T_BYTES = (size_t)2 * RSV * INSZ * sizeof(_Float16);       // 512 KB
    const size_t U16_BYTES  = (size_t)MTOT * RSV * sizeof(_Float16);           // 64 MB
    if (ws_size >= W16T_BYTES + U16_BYTES) {
        _Float16* W16T = (_Float16*)d_ws;
        _Float16* U16  = (_Float16*)((char*)d_ws + W16T_BYTES);
        esn_convw<<<dim3(64), dim3(256), 0, stream>>>(W, W16T);
        esn_gemm_f<<<dim3((MTOT / BM) * (RSV / BN)), dim3(256), 0, stream>>>(X, W16T, U16);
        esn_recur_f<<<dim3(BATCH * 8 * 2), dim3(256), 0, stream>>>(U16, D, OUT);
    } else {
        esn_gemm_fb<<<dim3((MTOT / BM) * (RSV / BN)), dim3(256), 0, stream>>>(X, W, OUT);
        esn_recur_fb<<<dim3(BATCH * RSV / 64), dim3(64), 0, stream>>>(OUT, D);
    }
}